// Round 1
// baseline (48.313 us; speedup 1.0000x reference)
//
#include <hip/hip_runtime.h>

// Problem constants (from reference):
//   N_TOTAL = 10100, D = 128, B = 2048
// F is sparse-in-values (avg ~33 nonzeros/row incl. diagonal 1.0) but stored dense.
// Strategy: per batch row, scan F row -> compact nonzero indices -> sparse
// accumulate E rows -> fused linear epilogue.

#define NTOT 10100
#define NV4  2525   // NTOT / 4 (exact)
#define DIM  128

__global__ __launch_bounds__(256) void friendship_kernel(
    const int*   __restrict__ uids,
    const float* __restrict__ F,
    const float* __restrict__ E,
    const float* __restrict__ W,
    const float* __restrict__ bias,
    float*       __restrict__ out)
{
    __shared__ unsigned short s_idx[NTOT + 12]; // nonzero column indices (cap >= NTOT, can't overflow)
    __shared__ int   s_cnt;
    __shared__ float s_red[256];
    __shared__ float s_agg[DIM];

    const int row = blockIdx.x;
    const int tid = threadIdx.x;
    const int uid = uids[row];
    const float* Frow = F + (size_t)uid * NTOT;

    if (tid == 0) s_cnt = 0;
    __syncthreads();

    // ---- Phase 1: scan F row (float4-vectorized), compact nonzeros ----
    const float4* Frow4 = (const float4*)Frow;  // row base 16B-aligned: uid*40400 % 16 == 0
    for (int i = tid; i < NV4; i += 256) {
        float4 v = Frow4[i];
        int n = i * 4;
        if (v.x != 0.0f) { int p = atomicAdd(&s_cnt, 1); s_idx[p] = (unsigned short)(n + 0); }
        if (v.y != 0.0f) { int p = atomicAdd(&s_cnt, 1); s_idx[p] = (unsigned short)(n + 1); }
        if (v.z != 0.0f) { int p = atomicAdd(&s_cnt, 1); s_idx[p] = (unsigned short)(n + 2); }
        if (v.w != 0.0f) { int p = atomicAdd(&s_cnt, 1); s_idx[p] = (unsigned short)(n + 3); }
    }
    __syncthreads();

    const int cnt = s_cnt;
    const int d   = tid & (DIM - 1);  // output dim this thread owns
    const int g   = tid >> 7;         // entry-group (0/1)

    // ---- Phase 2: aggregated[d] = sum over nonzeros w * E[n][d] ----
    float acc = 0.0f;
    for (int k = g; k < cnt; k += 2) {
        int   n = s_idx[k];
        float w = Frow[n];                       // broadcast load, L1/L2 hit (row just streamed)
        acc += w * E[(size_t)n * DIM + d];       // coalesced across d
    }
    s_red[tid] = acc;
    __syncthreads();
    if (tid < DIM) s_agg[tid] = s_red[tid] + s_red[tid + DIM];
    __syncthreads();

    // ---- Phase 3: out[j] = bias[j] + sum_d agg[d] * W[j*DIM + d] ----
    // thread (j = tid&127, g = tid>>7) covers d in [g*64, g*64+64)
    const int j = d;
    float part = 0.0f;
    const float4* W4 = (const float4*)(W + (size_t)j * DIM + g * 64); // 256B-aligned
    #pragma unroll
    for (int q = 0; q < 16; ++q) {
        float4 wv = W4[q];
        int dd = g * 64 + q * 4;
        part += wv.x * s_agg[dd + 0] + wv.y * s_agg[dd + 1]
              + wv.z * s_agg[dd + 2] + wv.w * s_agg[dd + 3];
    }
    s_red[tid] = part;   // safe: all prior s_red reads were before the last barrier
    __syncthreads();
    if (tid < DIM) out[(size_t)row * DIM + tid] = bias[tid] + s_red[tid] + s_red[tid + DIM];
}

extern "C" void kernel_launch(void* const* d_in, const int* in_sizes, int n_in,
                              void* d_out, int out_size, void* d_ws, size_t ws_size,
                              hipStream_t stream) {
    const int*   uids = (const int*)  d_in[0];
    const float* F    = (const float*)d_in[1];
    const float* E    = (const float*)d_in[2];
    const float* W    = (const float*)d_in[3];
    const float* bias = (const float*)d_in[4];
    float*       out  = (float*)d_out;

    const int B = in_sizes[0];  // 2048
    friendship_kernel<<<B, 256, 0, stream>>>(uids, F, E, W, bias, out);
}

// Round 2
// 40.452 us; speedup vs baseline: 1.1943x; 1.1943x over previous
//
#include <hip/hip_runtime.h>

// N_TOTAL = 10100, D = 128, B = 2048. F dense-stored but ~33 nnz/row.
// One block per batch row: scan F row -> compact (idx, weight) pairs into LDS
// -> sparse-accumulate E rows (unrolled x4 for MLP) -> fused linear epilogue.

#define NTOT 10100
#define NV4  2525    // NTOT / 4 (exact)
#define DIM  128
#define CAP  1024    // compaction capacity; nnz ~ Poisson(32), dense fallback if exceeded
#define TPB  512
#define NGRP 4       // TPB / DIM entry-groups

__global__ __launch_bounds__(TPB) void friendship_kernel(
    const int*   __restrict__ uids,
    const float* __restrict__ F,
    const float* __restrict__ E,
    const float* __restrict__ W,
    const float* __restrict__ bias,
    float*       __restrict__ out)
{
    __shared__ int   s_idx[CAP];
    __shared__ float s_w[CAP];
    __shared__ int   s_cnt;
    __shared__ float s_red[TPB];
    __shared__ float s_agg[DIM];

    const int row = blockIdx.x;
    const int tid = threadIdx.x;
    const int uid = uids[row];
    const float* Frow = F + (size_t)uid * NTOT;

    if (tid == 0) s_cnt = 0;
    __syncthreads();

    // ---- Phase 1: float4 scan of the F row, compact (n, w) into LDS ----
    const float4* Frow4 = (const float4*)Frow;  // uid*40400 % 16 == 0 -> aligned
    for (int i = tid; i < NV4; i += TPB) {
        float4 v = Frow4[i];
        int n = i * 4;
        if (v.x != 0.0f) { int p = atomicAdd(&s_cnt, 1); if (p < CAP) { s_idx[p] = n + 0; s_w[p] = v.x; } }
        if (v.y != 0.0f) { int p = atomicAdd(&s_cnt, 1); if (p < CAP) { s_idx[p] = n + 1; s_w[p] = v.y; } }
        if (v.z != 0.0f) { int p = atomicAdd(&s_cnt, 1); if (p < CAP) { s_idx[p] = n + 2; s_w[p] = v.z; } }
        if (v.w != 0.0f) { int p = atomicAdd(&s_cnt, 1); if (p < CAP) { s_idx[p] = n + 3; s_w[p] = v.w; } }
    }
    __syncthreads();

    const int cnt = s_cnt;
    const int d   = tid & (DIM - 1);  // owned output dim
    const int g   = tid >> 7;         // entry-group 0..3

    // ---- Phase 2: aggregated[d] = sum_k w_k * E[n_k][d] ----
    float acc = 0.0f;
    if (cnt <= CAP) {
        int k = g;
        for (; k + 3 * NGRP < cnt; k += 4 * NGRP) {
            int   n0 = s_idx[k],            n1 = s_idx[k +     NGRP];
            int   n2 = s_idx[k + 2 * NGRP], n3 = s_idx[k + 3 * NGRP];
            float w0 = s_w[k],              w1 = s_w[k +     NGRP];
            float w2 = s_w[k + 2 * NGRP],   w3 = s_w[k + 3 * NGRP];
            float e0 = E[(size_t)n0 * DIM + d];
            float e1 = E[(size_t)n1 * DIM + d];
            float e2 = E[(size_t)n2 * DIM + d];
            float e3 = E[(size_t)n3 * DIM + d];
            acc += w0 * e0; acc += w1 * e1; acc += w2 * e2; acc += w3 * e3;
        }
        for (; k < cnt; k += NGRP)
            acc += s_w[k] * E[(size_t)s_idx[k] * DIM + d];
    } else {
        // dense fallback (never taken for this data; guarantees correctness)
        for (int n = g; n < NTOT; n += NGRP)
            acc += Frow[n] * E[(size_t)n * DIM + d];
    }
    s_red[tid] = acc;
    __syncthreads();
    if (tid < DIM)
        s_agg[tid] = s_red[tid] + s_red[tid + DIM] + s_red[tid + 2 * DIM] + s_red[tid + 3 * DIM];
    __syncthreads();

    // ---- Phase 3: out[j] = bias[j] + sum_d agg[d] * W[j][d] ----
    const int j = d;                         // output feature
    float part = 0.0f;
    const float4* W4 = (const float4*)(W + (size_t)j * DIM + g * 32);
    #pragma unroll
    for (int q = 0; q < 8; ++q) {
        float4 wv = W4[q];
        int dd = g * 32 + q * 4;
        part += wv.x * s_agg[dd + 0] + wv.y * s_agg[dd + 1]
              + wv.z * s_agg[dd + 2] + wv.w * s_agg[dd + 3];
    }
    s_red[tid] = part;
    __syncthreads();
    if (tid < DIM)
        out[(size_t)row * DIM + tid] = bias[tid] + s_red[tid] + s_red[tid + DIM]
                                     + s_red[tid + 2 * DIM] + s_red[tid + 3 * DIM];
}

extern "C" void kernel_launch(void* const* d_in, const int* in_sizes, int n_in,
                              void* d_out, int out_size, void* d_ws, size_t ws_size,
                              hipStream_t stream) {
    const int*   uids = (const int*)  d_in[0];
    const float* F    = (const float*)d_in[1];
    const float* E    = (const float*)d_in[2];
    const float* W    = (const float*)d_in[3];
    const float* bias = (const float*)d_in[4];
    float*       out  = (float*)d_out;

    const int B = in_sizes[0];  // 2048
    friendship_kernel<<<B, TPB, 0, stream>>>(uids, F, E, W, bias, out);
}

// Round 3
// 30.700 us; speedup vs baseline: 1.5737x; 1.3176x over previous
//
#include <hip/hip_runtime.h>

// N_TOTAL = 10100, D = 128, B = 2048. F dense-stored but ~33 nnz/row.
// One block per batch row:
//   P1: float4 scan of F row, predicated single-atomic compaction of (idx,w)
//   P2: sparse accumulate E rows (x4 unrolled, coalesced over d)
//   P3: fused linear out = agg @ W^T + b with COALESCED W reads
//       (each 32-lane group owns one output j; half-wave shuffle reduce)

#define NTOT 10100
#define NV4  2525    // NTOT / 4 exact
#define DIM  128
#define CAP  1024    // nnz ~ Poisson(32); dense fallback if ever exceeded
#define TPB  512
#define NGRP 4       // TPB / DIM

__global__ __launch_bounds__(TPB) void friendship_kernel(
    const int*   __restrict__ uids,
    const float* __restrict__ F,
    const float* __restrict__ E,
    const float* __restrict__ W,
    const float* __restrict__ bias,
    float*       __restrict__ out)
{
    __shared__ int   s_idx[CAP];
    __shared__ float s_w[CAP];
    __shared__ int   s_cnt;
    __shared__ float s_red[TPB];
    __shared__ float s_agg[DIM];
    __shared__ float s_out[DIM];

    const int row = blockIdx.x;
    const int tid = threadIdx.x;
    const int uid = uids[row];
    const float* Frow = F + (size_t)uid * NTOT;

    if (tid == 0) s_cnt = 0;
    __syncthreads();

    // ---- Phase 1: scan + compact. One atomic per nonzero-containing chunk ----
    const float4* Frow4 = (const float4*)Frow;  // uid*40400 % 16 == 0 -> aligned
    for (int i = tid; i < NV4; i += TPB) {
        float4 v = Frow4[i];
        int n = i * 4;
        bool ba = v.x != 0.0f, bb = v.y != 0.0f, bc = v.z != 0.0f, bd = v.w != 0.0f;
        int  m  = (int)ba + (int)bb + (int)bc + (int)bd;
        if (m) {
            int p = atomicAdd(&s_cnt, m);
            if (p + m <= CAP) {
                if (ba) { s_idx[p] = n;     s_w[p] = v.x; ++p; }
                if (bb) { s_idx[p] = n + 1; s_w[p] = v.y; ++p; }
                if (bc) { s_idx[p] = n + 2; s_w[p] = v.z; ++p; }
                if (bd) { s_idx[p] = n + 3; s_w[p] = v.w; ++p; }
            }
        }
    }
    __syncthreads();

    const int cnt = s_cnt;
    const int d   = tid & (DIM - 1);
    const int g   = tid >> 7;          // 0..3

    // ---- Phase 2: agg[d] = sum_k w_k * E[n_k][d] ----
    float acc = 0.0f;
    if (cnt <= CAP) {
        int k = g;
        for (; k + 3 * NGRP < cnt; k += 4 * NGRP) {
            int   n0 = s_idx[k],            n1 = s_idx[k +     NGRP];
            int   n2 = s_idx[k + 2 * NGRP], n3 = s_idx[k + 3 * NGRP];
            float w0 = s_w[k],              w1 = s_w[k +     NGRP];
            float w2 = s_w[k + 2 * NGRP],   w3 = s_w[k + 3 * NGRP];
            acc += w0 * E[(size_t)n0 * DIM + d];
            acc += w1 * E[(size_t)n1 * DIM + d];
            acc += w2 * E[(size_t)n2 * DIM + d];
            acc += w3 * E[(size_t)n3 * DIM + d];
        }
        for (; k < cnt; k += NGRP)
            acc += s_w[k] * E[(size_t)s_idx[k] * DIM + d];
    } else {
        for (int n = g; n < NTOT; n += NGRP)   // never taken; correctness net
            acc += Frow[n] * E[(size_t)n * DIM + d];
    }
    s_red[tid] = acc;
    __syncthreads();
    if (tid < DIM)
        s_agg[tid] = s_red[tid] + s_red[tid + DIM] + s_red[tid + 2 * DIM] + s_red[tid + 3 * DIM];
    __syncthreads();

    // ---- Phase 3: out[j] = bias[j] + sum_d agg[d]*W[j][d], coalesced W ----
    // Lanes read consecutive float4s of W; each 32-lane group owns one j.
    const float4* W4 = (const float4*)W;
    #pragma unroll
    for (int q = 0; q < 8; ++q) {
        int i4 = tid + TPB * q;              // 0..4095 over q
        float4 wv = W4[i4];                  // fully coalesced
        int dd = (i4 & 31) * 4;
        float p = wv.x * s_agg[dd]     + wv.y * s_agg[dd + 1]
                + wv.z * s_agg[dd + 2] + wv.w * s_agg[dd + 3];
        p += __shfl_xor(p, 16);
        p += __shfl_xor(p, 8);
        p += __shfl_xor(p, 4);
        p += __shfl_xor(p, 2);
        p += __shfl_xor(p, 1);
        if ((tid & 31) == 0) s_out[i4 >> 5] = p;
    }
    __syncthreads();
    if (tid < DIM)
        out[(size_t)row * DIM + tid] = bias[tid] + s_out[tid];
}

extern "C" void kernel_launch(void* const* d_in, const int* in_sizes, int n_in,
                              void* d_out, int out_size, void* d_ws, size_t ws_size,
                              hipStream_t stream) {
    const int*   uids = (const int*)  d_in[0];
    const float* F    = (const float*)d_in[1];
    const float* E    = (const float*)d_in[2];
    const float* W    = (const float*)d_in[3];
    const float* bias = (const float*)d_in[4];
    float*       out  = (float*)d_out;

    const int B = in_sizes[0];  // 2048
    friendship_kernel<<<B, TPB, 0, stream>>>(uids, F, E, W, bias, out);
}